// Round 18
// baseline (676.233 us; speedup 1.0000x reference)
//
#include <hip/hip_runtime.h>
#include <math.h>

#define NEGF -1000000000.0f
#define EPSF 1e-7f

// B=32, T=256, IN=64, H=128, 4H=512, TOP_K=5

typedef float v4f __attribute__((ext_vector_type(4)));
#define FMA4(a, b, c) __builtin_elementwise_fma((a), (b), (c))

// Raw barrier: LDS-only drain + s_barrier (keeps global prefetch in flight).
#define RAWBAR() asm volatile("s_waitcnt lgkmcnt(0)\n\ts_barrier" ::: "memory")

__device__ __forceinline__ float fsigmoid(float x) {
  return 1.0f / (1.0f + __expf(-x));               // overflow -> correct limit
}
__device__ __forceinline__ float ftanh(float x) {
  return 1.0f - 2.0f / (1.0f + __expf(2.0f * x));  // limits +-1: correct
}

// wave64 all-reduce sum via DPP (row_shr 1/2/4/8 + row_bcast 15/31), ~35 cyc.
__device__ __forceinline__ float wave_allsum(float v) {
#if __has_builtin(__builtin_amdgcn_update_dpp) && __has_builtin(__builtin_amdgcn_readlane)
  float f = v;
#define DPPSTEP(ctrl, rmask) { \
    int t = __builtin_amdgcn_update_dpp(0, __builtin_bit_cast(int, f), \
                                        ctrl, rmask, 0xf, true); \
    f += __builtin_bit_cast(float, t); }
  DPPSTEP(0x111, 0xf)   // row_shr:1
  DPPSTEP(0x112, 0xf)   // row_shr:2
  DPPSTEP(0x114, 0xf)   // row_shr:4
  DPPSTEP(0x118, 0xf)   // row_shr:8  -> lane15 of each row has row sum
  DPPSTEP(0x142, 0xa)   // row_bcast:15 into rows 1,3
  DPPSTEP(0x143, 0x8)   // row_bcast:31 into row 3 -> lane 63 = total
#undef DPPSTEP
  return __builtin_bit_cast(float,
      __builtin_amdgcn_readlane(__builtin_bit_cast(int, f), 63));
#else
  for (int off = 1; off < 64; off <<= 1) v += __shfl_xor(v, off, 64);
  return v;
#endif
}

// Kernel 1: xw[b][t][g] = x[b][t] . W_ih[g] + (b_ih[g]+b_hh[g])
// EXACT round-3 version (proven).
__global__ __launch_bounds__(512) void xw_kernel(
    const float* __restrict__ x, const float* __restrict__ W_ih,
    const float* __restrict__ b_ih, const float* __restrict__ b_hh,
    float* __restrict__ xw)
{
  const int t0 = blockIdx.x * 32;
  const int b  = blockIdx.y;
  const int g  = threadIdx.x;

  __shared__ float sx[32 * 64];              // 8 KB
  ((float4*)sx)[threadIdx.x] =
      ((const float4*)(x + (size_t)(b * 256 + t0) * 64))[threadIdx.x];

  const float4* wr = (const float4*)(W_ih + (size_t)g * 64);
  float4 w0 = wr[0],  w1 = wr[1],  w2 = wr[2],  w3 = wr[3],
         w4 = wr[4],  w5 = wr[5],  w6 = wr[6],  w7 = wr[7],
         w8 = wr[8],  w9 = wr[9],  w10 = wr[10], w11 = wr[11],
         w12 = wr[12], w13 = wr[13], w14 = wr[14], w15 = wr[15];
  const float bias = b_ih[g] + b_hh[g];
  __syncthreads();

  float* dst = xw + (size_t)(b * 256 + t0) * 512 + g;
  for (int tt = 0; tt < 32; ++tt) {
    const float4* xr = (const float4*)(sx + tt * 64);
    float a0 = 0.0f, a1 = 0.0f, a2 = 0.0f, a3 = 0.0f;
#define XSTEP(j) { float4 hv = xr[j]; \
    a0 = fmaf(w##j.x, hv.x, a0); a1 = fmaf(w##j.y, hv.y, a1); \
    a2 = fmaf(w##j.z, hv.z, a2); a3 = fmaf(w##j.w, hv.w, a3); }
    XSTEP(0) XSTEP(1) XSTEP(2) XSTEP(3) XSTEP(4) XSTEP(5) XSTEP(6) XSTEP(7)
    XSTEP(8) XSTEP(9) XSTEP(10) XSTEP(11) XSTEP(12) XSTEP(13) XSTEP(14) XSTEP(15)
#undef XSTEP
    dst[(size_t)tt * 512] = (a0 + a1) + (a2 + a3) + bias;
  }
}

// Kernel 2: recurrence, 640 threads (10 waves): ROLE SPLIT vs R16 (286us):
//   waves 0-7 : Phase A only (identical gate/K mapping to R16's 512 thr)
//   waves 8,9 : Phase B + tail only (1 elem/lane, j = (wid-8)*64 + l)
// Per step the cell waves run tail(i-1) CONCURRENTLY with the compute
// waves' PhaseA(i) — the ~150-200cyc tail (dn tanh+allsum+top5+gn rcp)
// leaves the critical path (in R16 waves 0,1 ran PhaseB+tail+PhaseA
// serially). Sync structure, LDS layout, arithmetic: byte-identical.
// R17's all-wave replication regressed (4x per-lane sh_part reads on the
// single LDS pipe); this split adds NO LDS traffic.
// Tripwire: VGPR ~108 / WRITE_SIZE 48KB.
//
// DELTA CANCELLATION (unchanged):
//   s[t] = a + d[t]; delta = a + top5(d)[4] + EPS  =>  w[t] = d[t]-t5v4-EPS
//   independent of a. Sparse attention = 4 register-indexed LDS gathers,
//   addresses known from the PREVIOUS step (prefetched before S1).
__global__
__attribute__((amdgpu_flat_work_group_size(640, 640), amdgpu_waves_per_eu(2)))
void lstm_attn(
    const float* __restrict__ xw, const float* __restrict__ W_hh,
    const float* __restrict__ w_t, float* __restrict__ out)
{
  const int b   = blockIdx.x;
  const int tid = threadIdx.x;
  const int l   = tid & 63;       // lane
  const int wid = tid >> 6;       // 0..9
  const int g2  = tid & 255;      // gates g2, g2+256 (compute waves)
  const int q   = (tid >> 8) & 1; // K-half 0/1 (clamped: in-bounds for all)
  const int cw  = wid - 8;        // cell-wave id 0/1 (valid when wid>=8)

  __shared__ float ho[257 * 128];     // fp32 h history (131584 B)
  __shared__ float sh_part[2 * 512];  // gate partials [q][gate] (4 KB)
  __shared__ float sh_d[8];           // d[t] cache (raw-score steps)
  __shared__ float sh_pa[2];          // partial a (i<5 path)
  __shared__ float sh_dn[2];          // partial dn (every step)

  // one-time weight load: 2 gate rows x 16 v4f = 32 named v4f (compute waves;
  // cell waves load valid-but-unused addresses, values never read)
  const v4f* pA = (const v4f*)(W_hh + (size_t)g2 * 128 + (q << 6));
  const v4f* pB = (const v4f*)(W_hh + (size_t)(g2 + 256) * 128 + (q << 6));
  v4f wA0 = pA[0],  wA1 = pA[1],  wA2 = pA[2],  wA3 = pA[3],
      wA4 = pA[4],  wA5 = pA[5],  wA6 = pA[6],  wA7 = pA[7],
      wA8 = pA[8],  wA9 = pA[9],  wA10 = pA[10], wA11 = pA[11],
      wA12 = pA[12], wA13 = pA[13], wA14 = pA[14], wA15 = pA[15];
  v4f wB0 = pB[0],  wB1 = pB[1],  wB2 = pB[2],  wB3 = pB[3],
      wB4 = pB[4],  wB5 = pB[5],  wB6 = pB[6],  wB7 = pB[7],
      wB8 = pB[8],  wB9 = pB[9],  wB10 = pB[10], wB11 = pB[11],
      wB12 = pB[12], wB13 = pB[13], wB14 = pB[14], wB15 = pB[15];

  // cell-wave per-lane persistent state: element j
  const int j = (cw << 6) + l;    // valid when wid>=8
  float cc = 0.0f;
  float wa = 0.0f, wb = 0.0f;
  float t5v0 = 0.0f, t5v1 = NEGF, t5v2 = NEGF, t5v3 = NEGF, t5v4 = NEGF;
  int   t5i0 = 0, t5i1 = 0, t5i2 = 0, t5i3 = 0;
  float gn0 = 0.0f, gn1 = 0.0f, gn2 = 0.0f, gn3 = 0.0f;
  int   ofs0 = 0, ofs1 = 0, ofs2 = 0, ofs3 = 0;

  if (wid >= 8) {
    wa = w_t[j]; wb = w_t[128 + j];
    ho[j] = 0.0f;                      // h(-1) = 0 (row 0)
    __builtin_amdgcn_s_setprio(1);     // cell waves are the stragglers
  }
  if (tid == 0) sh_d[0] = 0.0f;
  __syncthreads();   // one-time full sync

  const float* xwb = xw + (size_t)b * 256 * 512;
  float xcA = 0.0f, xcB = 0.0f;
  if (wid < 8 && q == 0 && wid < 4) { xcA = xwb[g2]; xcB = xwb[g2 + 256]; }

  for (int i = 0; i < 256; ++i) {
    const int rem = i + 1;

    if (wid < 8) {
      // ---- Phase A: 2 gate-partials, packed fp32 (32 pk-FMA/thread) ----
      v4f aA = {xcA, 0.0f, 0.0f, 0.0f};
      v4f aB = {xcB, 0.0f, 0.0f, 0.0f};
      if (wid < 4 && i < 255) {       // q==0 waves prefetch next xw
        const float* xn = xwb + (size_t)(i + 1) * 512;
        xcA = xn[g2]; xcB = xn[g2 + 256];
      }
      const v4f* hh4 = (const v4f*)(ho + i * 128 + (q << 6));
#define KS(k) { v4f hv = hh4[k]; \
      aA = FMA4(wA##k, hv, aA); aB = FMA4(wB##k, hv, aB); }
      KS(0) KS(1) KS(2) KS(3) KS(4) KS(5) KS(6) KS(7)
      KS(8) KS(9) KS(10) KS(11) KS(12) KS(13) KS(14) KS(15)
#undef KS
      float* sp = sh_part + (q << 9) + g2;
      sp[0]   = (aA.x + aA.y) + (aA.z + aA.w);
      sp[256] = (aB.x + aB.y) + (aB.z + aB.w);
    }

    // gather prefetch (cell waves): addresses from previous step's top-5;
    // ho rows are append-only so reading before the barrier is race-free.
    float hv0 = 0.0f, hv1 = 0.0f, hv2 = 0.0f, hv3 = 0.0f;
    if (wid >= 8 && i >= 5) {
      hv0 = ho[ofs0]; hv1 = ho[ofs1]; hv2 = ho[ofs2]; hv3 = ho[ofs3];
    }
    RAWBAR();                                             // S1

    // ---- Phase B: LSTM cell in waves 8,9 only (1 elem/lane) ----
    float hc = 0.0f, at = 0.0f;
    if (wid >= 8) {
      const float* s0 = sh_part + j;
      float Pi = s0[0]   + s0[512];
      float Pf = s0[128] + s0[640];
      float Pg = s0[256] + s0[768];
      float Po = s0[384] + s0[896];
      cc = fsigmoid(Pf) * cc + fsigmoid(Pi) * ftanh(Pg);
      hc = fsigmoid(Po) * ftanh(cc);
    }
    if (i < 5) {
      // raw-score path: needs block-wide a = sum over all 128 elements
      if (wid >= 8) {
        float pa = wave_allsum(ftanh(hc) * wa);
        if (l == 0) sh_pa[cw] = pa;
      }
      RAWBAR();                       // extra all-wave barrier (5 steps only)
      if (wid >= 8) {
        float a = sh_pa[0] + sh_pa[1];
        at = 0.0f;
        for (int t = 0; t <= i; ++t)
          at = fmaf(a + sh_d[t], ho[t * 128 + j], at);
      }
    } else if (wid >= 8) {
      at = gn0 * hv0;
      at = fmaf(gn1, hv1, at);
      at = fmaf(gn2, hv2, at);
      at = fmaf(gn3, hv3, at);
    }
    float hn = 0.0f;
    if (wid >= 8) {
      hn = hc + at;
      ho[rem * 128 + j] = hn;
      float pdn = wave_allsum(ftanh(hn) * wb);   // pre-S2 partial
      if (l == 0) sh_dn[cw] = pdn;
      if (i == 255) {
        out[b * 128 + j] = at;                   // attn_c
        if (cw == 0) {
          // attn_w: zero except at the <=4 above-threshold top-5 indices
          #pragma unroll
          for (int m = 0; m < 4; ++m) {
            int t = l + 64 * m;
            float val = 0.0f;
            if (t == t5i0) val = gn0;
            if (t == t5i1) val = gn1;
            if (t == t5i2) val = gn2;
            if (t == t5i3) val = gn3;
            out[4096 + b * 256 + t] = val;
          }
        }
      }
    }
    RAWBAR();                                             // S2

    // ---- tail (cell waves; overlaps compute waves' next Phase A) ----
    if (wid >= 8 && i < 255) {
      float dn = sh_dn[0] + sh_dn[1];
      if (cw == 0 && l == 0 && i < 4) sh_d[rem] = dn;
      // replicated top-5 (value,index) insert — identical in both waves
      float v = dn; int vi = rem;
      if (v > t5v0) { float tv = t5v0; int ti = t5i0; t5v0 = v; t5i0 = vi; v = tv; vi = ti; }
      if (v > t5v1) { float tv = t5v1; int ti = t5i1; t5v1 = v; t5i1 = vi; v = tv; vi = ti; }
      if (v > t5v2) { float tv = t5v2; int ti = t5i2; t5v2 = v; t5i2 = vi; v = tv; vi = ti; }
      if (v > t5v3) { float tv = t5v3; int ti = t5i3; t5v3 = v; t5i3 = vi; v = tv; vi = ti; }
      if (v > t5v4) { t5v4 = v; }
      // next step's normalized gather weights + offsets (delta cancellation)
      float g0 = fmaxf(t5v0 - t5v4 - EPSF, 0.0f);
      float g1 = fmaxf(t5v1 - t5v4 - EPSF, 0.0f);
      float g2f = fmaxf(t5v2 - t5v4 - EPSF, 0.0f);
      float g3 = fmaxf(t5v3 - t5v4 - EPSF, 0.0f);
      float inv = 1.0f / (((g0 + g1) + (g2f + g3)) + EPSF);
      gn0 = g0 * inv; gn1 = g1 * inv; gn2 = g2f * inv; gn3 = g3 * inv;
      ofs0 = (t5i0 << 7) + j; ofs1 = (t5i1 << 7) + j;
      ofs2 = (t5i2 << 7) + j; ofs3 = (t5i3 << 7) + j;
    }
  }
}

extern "C" void kernel_launch(void* const* d_in, const int* in_sizes, int n_in,
                              void* d_out, int out_size, void* d_ws, size_t ws_size,
                              hipStream_t stream) {
  const float* x    = (const float*)d_in[0];  // (32,256,64)
  const float* W_ih = (const float*)d_in[1];  // (512,64)
  const float* W_hh = (const float*)d_in[2];  // (512,128)
  const float* b_ih = (const float*)d_in[3];  // (512,)
  const float* b_hh = (const float*)d_in[4];  // (512,)
  const float* w_t  = (const float*)d_in[5];  // (256,1)
  float* out = (float*)d_out;                 // [0:4096) attn_c, [4096:12288) attn_w

  float* xw = (float*)d_ws;                   // 32*256*512 fp32 = 16 MB

  xw_kernel<<<dim3(8, 32), 512, 0, stream>>>(x, W_ih, b_ih, b_hh, xw);
  lstm_attn<<<dim3(32), 640, 0, stream>>>(xw, W_hh, w_t, out);
}

// Round 19
// 367.884 us; speedup vs baseline: 1.8382x; 1.8382x over previous
//
#include <hip/hip_runtime.h>
#include <math.h>

#define NEGF -1000000000.0f
#define EPSF 1e-7f

// B=32, T=256, IN=64, H=128, 4H=512, TOP_K=5

typedef float v4f __attribute__((ext_vector_type(4)));
#define FMA4(a, b, c) __builtin_elementwise_fma((a), (b), (c))

// Raw barrier: LDS-only drain + s_barrier (keeps global prefetch in flight).
#define RAWBAR() asm volatile("s_waitcnt lgkmcnt(0)\n\ts_barrier" ::: "memory")

__device__ __forceinline__ float fsigmoid(float x) {
  return 1.0f / (1.0f + __expf(-x));               // overflow -> correct limit
}
__device__ __forceinline__ float ftanh(float x) {
  return 1.0f - 2.0f / (1.0f + __expf(2.0f * x));  // limits +-1: correct
}

// wave64 all-reduce sum via DPP (row_shr 1/2/4/8 + row_bcast 15/31), ~35 cyc.
__device__ __forceinline__ float wave_allsum(float v) {
#if __has_builtin(__builtin_amdgcn_update_dpp) && __has_builtin(__builtin_amdgcn_readlane)
  float f = v;
#define DPPSTEP(ctrl, rmask) { \
    int t = __builtin_amdgcn_update_dpp(0, __builtin_bit_cast(int, f), \
                                        ctrl, rmask, 0xf, true); \
    f += __builtin_bit_cast(float, t); }
  DPPSTEP(0x111, 0xf)   // row_shr:1
  DPPSTEP(0x112, 0xf)   // row_shr:2
  DPPSTEP(0x114, 0xf)   // row_shr:4
  DPPSTEP(0x118, 0xf)   // row_shr:8  -> lane15 of each row has row sum
  DPPSTEP(0x142, 0xa)   // row_bcast:15 into rows 1,3
  DPPSTEP(0x143, 0x8)   // row_bcast:31 into row 3 -> lane 63 = total
#undef DPPSTEP
  return __builtin_bit_cast(float,
      __builtin_amdgcn_readlane(__builtin_bit_cast(int, f), 63));
#else
  for (int off = 1; off < 64; off <<= 1) v += __shfl_xor(v, off, 64);
  return v;
#endif
}

// Kernel 1: xw[b][t][g] = x[b][t] . W_ih[g] + (b_ih[g]+b_hh[g])
// EXACT round-3 version (proven; wide 256-block dispatch beats both the
// in-kernel prologue (R14/R15) and concurrent producers (R10)).
__global__ __launch_bounds__(512) void xw_kernel(
    const float* __restrict__ x, const float* __restrict__ W_ih,
    const float* __restrict__ b_ih, const float* __restrict__ b_hh,
    float* __restrict__ xw)
{
  const int t0 = blockIdx.x * 32;
  const int b  = blockIdx.y;
  const int g  = threadIdx.x;

  __shared__ float sx[32 * 64];              // 8 KB
  ((float4*)sx)[threadIdx.x] =
      ((const float4*)(x + (size_t)(b * 256 + t0) * 64))[threadIdx.x];

  const float4* wr = (const float4*)(W_ih + (size_t)g * 64);
  float4 w0 = wr[0],  w1 = wr[1],  w2 = wr[2],  w3 = wr[3],
         w4 = wr[4],  w5 = wr[5],  w6 = wr[6],  w7 = wr[7],
         w8 = wr[8],  w9 = wr[9],  w10 = wr[10], w11 = wr[11],
         w12 = wr[12], w13 = wr[13], w14 = wr[14], w15 = wr[15];
  const float bias = b_ih[g] + b_hh[g];
  __syncthreads();

  float* dst = xw + (size_t)(b * 256 + t0) * 512 + g;
  for (int tt = 0; tt < 32; ++tt) {
    const float4* xr = (const float4*)(sx + tt * 64);
    float a0 = 0.0f, a1 = 0.0f, a2 = 0.0f, a3 = 0.0f;
#define XSTEP(j) { float4 hv = xr[j]; \
    a0 = fmaf(w##j.x, hv.x, a0); a1 = fmaf(w##j.y, hv.y, a1); \
    a2 = fmaf(w##j.z, hv.z, a2); a3 = fmaf(w##j.w, hv.w, a3); }
    XSTEP(0) XSTEP(1) XSTEP(2) XSTEP(3) XSTEP(4) XSTEP(5) XSTEP(6) XSTEP(7)
    XSTEP(8) XSTEP(9) XSTEP(10) XSTEP(11) XSTEP(12) XSTEP(13) XSTEP(14) XSTEP(15)
#undef XSTEP
    dst[(size_t)tt * 512] = (a0 + a1) + (a2 + a3) + bias;
  }
}

// Kernel 2: full recurrence, one block per batch, 512 threads (8 waves,
// 2/SIMD). BEST MEASURED CONFIGURATION (R16: 286.4us lstm, 368.4 total;
// statistically tied with R13). Restored verbatim after R17 (replication,
// -LDS-pipe) and R18 (role-split, -spill) both regressed.
//
// Structure: Phase A = 2 gates x 64-K-half per thread (32 v4f weights,
// 32 pk-FMA); Phase B split across waves 0+1 (1 elem/lane); 2 RAWBARs
// (provably minimal: S1 orders parts-write->read, S2 orders h-write->read);
// tail (dn allsum + top-5 + gn) on waves 0,1 post-S2.
//
// DELTA CANCELLATION:
//   s[t] = a + d[t]; delta = a + top5(d)[4] + EPS  =>  w[t] = d[t]-t5v4-EPS
//   independent of a. Sparse attention = 4 register-indexed LDS gathers,
//   addresses known from the PREVIOUS step (prefetched before S1).
__global__
__attribute__((amdgpu_flat_work_group_size(512, 512), amdgpu_waves_per_eu(2, 2)))
void lstm_attn(
    const float* __restrict__ xw, const float* __restrict__ W_hh,
    const float* __restrict__ w_t, float* __restrict__ out)
{
  const int b   = blockIdx.x;
  const int tid = threadIdx.x;
  const int l   = tid & 63;       // lane
  const int wid = tid >> 6;
  const int g2  = tid & 255;      // gates g2, g2+256
  const int q   = tid >> 8;       // K-half 0/1 (wave-uniform)

  __shared__ float ho[257 * 128];     // fp32 h history (131584 B)
  __shared__ float sh_part[2 * 512];  // gate partials [q][gate] (4 KB)
  __shared__ float sh_d[8];           // d[t] cache (raw-score steps)
  __shared__ float sh_pa[2];          // partial a (i<5 path)
  __shared__ float sh_dn[2];          // partial dn (every step)

  // one-time weight load: 2 gate rows x 16 v4f = 32 named v4f
  const v4f* pA = (const v4f*)(W_hh + (size_t)g2 * 128 + (q << 6));
  const v4f* pB = (const v4f*)(W_hh + (size_t)(g2 + 256) * 128 + (q << 6));
  v4f wA0 = pA[0],  wA1 = pA[1],  wA2 = pA[2],  wA3 = pA[3],
      wA4 = pA[4],  wA5 = pA[5],  wA6 = pA[6],  wA7 = pA[7],
      wA8 = pA[8],  wA9 = pA[9],  wA10 = pA[10], wA11 = pA[11],
      wA12 = pA[12], wA13 = pA[13], wA14 = pA[14], wA15 = pA[15];
  v4f wB0 = pB[0],  wB1 = pB[1],  wB2 = pB[2],  wB3 = pB[3],
      wB4 = pB[4],  wB5 = pB[5],  wB6 = pB[6],  wB7 = pB[7],
      wB8 = pB[8],  wB9 = pB[9],  wB10 = pB[10], wB11 = pB[11],
      wB12 = pB[12], wB13 = pB[13], wB14 = pB[14], wB15 = pB[15];

  // waves 0,1 per-lane persistent state: element j
  const int j = (wid << 6) + l;
  float cc = 0.0f;
  float wa = 0.0f, wb = 0.0f;
  float t5v0 = 0.0f, t5v1 = NEGF, t5v2 = NEGF, t5v3 = NEGF, t5v4 = NEGF;
  int   t5i0 = 0, t5i1 = 0, t5i2 = 0, t5i3 = 0;
  float gn0 = 0.0f, gn1 = 0.0f, gn2 = 0.0f, gn3 = 0.0f;
  int   ofs0 = 0, ofs1 = 0, ofs2 = 0, ofs3 = 0;

  if (wid < 2) {
    wa = w_t[j]; wb = w_t[128 + j];
    ho[j] = 0.0f;                      // h(-1) = 0 (row 0)
    __builtin_amdgcn_s_setprio(1);     // cell waves are barrier stragglers
  }
  if (tid == 0) sh_d[0] = 0.0f;
  __syncthreads();   // one-time full sync

  const float* xwb = xw + (size_t)b * 256 * 512;
  float xcA = 0.0f, xcB = 0.0f;
  if (q == 0) { xcA = xwb[g2]; xcB = xwb[g2 + 256]; }

  for (int i = 0; i < 256; ++i) {
    const int rem = i + 1;

    // ---- Phase A: 2 gate-partials, packed fp32 (32 pk-FMA/thread) ----
    v4f aA = {xcA, 0.0f, 0.0f, 0.0f};
    v4f aB = {xcB, 0.0f, 0.0f, 0.0f};
    if (q == 0 && i < 255) {          // prefetch next step's xw (stays in
      const float* xn = xwb + (size_t)(i + 1) * 512;     // flight over bars)
      xcA = xn[g2]; xcB = xn[g2 + 256];
    }
    const v4f* hh4 = (const v4f*)(ho + i * 128 + (q << 6));
#define KS(k) { v4f hv = hh4[k]; \
    aA = FMA4(wA##k, hv, aA); aB = FMA4(wB##k, hv, aB); }
    KS(0) KS(1) KS(2) KS(3) KS(4) KS(5) KS(6) KS(7)
    KS(8) KS(9) KS(10) KS(11) KS(12) KS(13) KS(14) KS(15)
#undef KS
    {
      float* sp = sh_part + (q << 9) + g2;
      sp[0]   = (aA.x + aA.y) + (aA.z + aA.w);
      sp[256] = (aB.x + aB.y) + (aB.z + aB.w);
    }

    // gather prefetch: addresses known from previous step's top-5; ho rows
    // are append-only so reading before the barrier is race-free.
    float hv0 = 0.0f, hv1 = 0.0f, hv2 = 0.0f, hv3 = 0.0f;
    if (wid < 2 && i >= 5) {
      hv0 = ho[ofs0]; hv1 = ho[ofs1]; hv2 = ho[ofs2]; hv3 = ho[ofs3];
    }
    RAWBAR();                                             // S1

    // ---- Phase B: LSTM cell, split across waves 0 and 1 (1 elem/lane) ----
    float hc = 0.0f, at = 0.0f;
    if (wid < 2) {
      const float* s0 = sh_part + j;
      float Pi = s0[0]   + s0[512];
      float Pf = s0[128] + s0[640];
      float Pg = s0[256] + s0[768];
      float Po = s0[384] + s0[896];
      cc = fsigmoid(Pf) * cc + fsigmoid(Pi) * ftanh(Pg);
      hc = fsigmoid(Po) * ftanh(cc);
    }
    if (i < 5) {
      // raw-score path: needs block-wide a = sum over all 128 elements
      if (wid < 2) {
        float pa = wave_allsum(ftanh(hc) * wa);
        if (l == 0) sh_pa[wid] = pa;
      }
      RAWBAR();                       // extra all-wave barrier (5 steps only)
      if (wid < 2) {
        float a = sh_pa[0] + sh_pa[1];
        at = 0.0f;
        for (int t = 0; t <= i; ++t)
          at = fmaf(a + sh_d[t], ho[t * 128 + j], at);
      }
    } else if (wid < 2) {
      at = gn0 * hv0;
      at = fmaf(gn1, hv1, at);
      at = fmaf(gn2, hv2, at);
      at = fmaf(gn3, hv3, at);
    }
    if (wid < 2) {
      float hn = hc + at;
      ho[rem * 128 + j] = hn;
      float pdn = wave_allsum(ftanh(hn) * wb);   // pre-S2 partial
      if (l == 0) sh_dn[wid] = pdn;
      if (i == 255) {
        out[b * 128 + j] = at;                   // attn_c
        if (wid == 0) {
          // attn_w: zero except at the <=4 above-threshold top-5 indices
          #pragma unroll
          for (int m = 0; m < 4; ++m) {
            int t = l + 64 * m;
            float val = 0.0f;
            if (t == t5i0) val = gn0;
            if (t == t5i1) val = gn1;
            if (t == t5i2) val = gn2;
            if (t == t5i3) val = gn3;
            out[4096 + b * 256 + t] = val;
          }
        }
      }
    }
    RAWBAR();                                             // S2

    // ---- tail (waves 0,1; off critical path of the other 6 waves) ----
    if (wid < 2 && i < 255) {
      float dn = sh_dn[0] + sh_dn[1];
      if (wid == 0 && l == 0 && i < 4) sh_d[rem] = dn;
      // replicated top-5 (value,index) insert — identical in both waves
      float v = dn; int vi = rem;
      if (v > t5v0) { float tv = t5v0; int ti = t5i0; t5v0 = v; t5i0 = vi; v = tv; vi = ti; }
      if (v > t5v1) { float tv = t5v1; int ti = t5i1; t5v1 = v; t5i1 = vi; v = tv; vi = ti; }
      if (v > t5v2) { float tv = t5v2; int ti = t5i2; t5v2 = v; t5i2 = vi; v = tv; vi = ti; }
      if (v > t5v3) { float tv = t5v3; int ti = t5i3; t5v3 = v; t5i3 = vi; v = tv; vi = ti; }
      if (v > t5v4) { t5v4 = v; }
      // next step's normalized gather weights + offsets (delta cancellation)
      float g0 = fmaxf(t5v0 - t5v4 - EPSF, 0.0f);
      float g1 = fmaxf(t5v1 - t5v4 - EPSF, 0.0f);
      float g2f = fmaxf(t5v2 - t5v4 - EPSF, 0.0f);
      float g3 = fmaxf(t5v3 - t5v4 - EPSF, 0.0f);
      float inv = 1.0f / (((g0 + g1) + (g2f + g3)) + EPSF);
      gn0 = g0 * inv; gn1 = g1 * inv; gn2 = g2f * inv; gn3 = g3 * inv;
      ofs0 = (t5i0 << 7) + j; ofs1 = (t5i1 << 7) + j;
      ofs2 = (t5i2 << 7) + j; ofs3 = (t5i3 << 7) + j;
    }
  }
}

extern "C" void kernel_launch(void* const* d_in, const int* in_sizes, int n_in,
                              void* d_out, int out_size, void* d_ws, size_t ws_size,
                              hipStream_t stream) {
  const float* x    = (const float*)d_in[0];  // (32,256,64)
  const float* W_ih = (const float*)d_in[1];  // (512,64)
  const float* W_hh = (const float*)d_in[2];  // (512,128)
  const float* b_ih = (const float*)d_in[3];  // (512,)
  const float* b_hh = (const float*)d_in[4];  // (512,)
  const float* w_t  = (const float*)d_in[5];  // (256,1)
  float* out = (float*)d_out;                 // [0:4096) attn_c, [4096:12288) attn_w

  float* xw = (float*)d_ws;                   // 32*256*512 fp32 = 16 MB

  xw_kernel<<<dim3(8, 32), 512, 0, stream>>>(x, W_ih, b_ih, b_hh, xw);
  lstm_attn<<<dim3(32), 512, 0, stream>>>(xw, W_hh, w_t, out);
}